// Round 12
// baseline (6698.322 us; speedup 1.0000x reference)
//
#include <hip/hip_runtime.h>
#include <stdint.h>

#define NPTS 8192
#define BATCH 2
#define KNN 20
#define BN_EPS 1e-5f

// ---------------------------------------------------------------------------
// transpose x [B,3,N] -> xt [B,N,4] (pad 4th chan with 0) + squared norms
// (xt doubles as the channel-block-major XT4 for C=4: XT4[b][0][n] = xt[b][n])
// ---------------------------------------------------------------------------
__global__ __launch_bounds__(256) void k_xt(const float* __restrict__ x,
                                            float* __restrict__ xt,
                                            float* __restrict__ nrm) {
  int i = blockIdx.x * 256 + threadIdx.x;          // over B*N
  int b = i / NPTS, n = i % NPTS;
  float x0 = x[((size_t)b * 3 + 0) * NPTS + n];
  float x1 = x[((size_t)b * 3 + 1) * NPTS + n];
  float x2 = x[((size_t)b * 3 + 2) * NPTS + n];
  float4 v = make_float4(x0, x1, x2, 0.f);
  reinterpret_cast<float4*>(xt)[i] = v;
  // mimic np.sum(x*x) order: ((x0^2 + x1^2) + x2^2), no fma
  float s0 = x0 * x0, s1 = x1 * x1, s2 = x2 * x2;
  nrm[i] = (s0 + s1) + s2;
}

// ---------------------------------------------------------------------------
// build stacked weights A2[2O][Cpad]: rows 0..O-1 = Wn, rows O..2O-1 = Wc-Wn
// (zero-pad c >= Creal; W is [O][2*Creal] row-major)
// ---------------------------------------------------------------------------
__global__ __launch_bounds__(256) void k_prep(const float* __restrict__ W,
                                              float* __restrict__ A2,
                                              int O, int Creal, int Cpad) {
  int i = blockIdx.x * 256 + threadIdx.x;
  if (i >= O * Cpad) return;
  int o = i / Cpad, c = i % Cpad;
  float wn = (c < Creal) ? W[(size_t)o * 2 * Creal + c] : 0.f;
  float wc = (c < Creal) ? W[(size_t)o * 2 * Creal + Creal + c] : 0.f;
  A2[(size_t)o * Cpad + c] = wn;
  A2[(size_t)(O + o) * Cpad + c] = wc - wn;
}

// ---------------------------------------------------------------------------
// transpose a channel slice of Xcat to channel-block-major XT4[b][c4][n]
// (float4 = channels 4c4..4c4+3 of point n) AND compute squared norms
// (replaces k_norms; same fmaf order -> bitwise-identical nrm).
// Block: 64 points.  Row reads coalesced; XT writes coalesced (1 KB/instr).
// ---------------------------------------------------------------------------
template <int C>
__global__ __launch_bounds__(256) void k_tr(const float* __restrict__ X,
                                            int S, int coff,
                                            float4* __restrict__ XT,
                                            float* __restrict__ nrm) {
  constexpr int C4 = C / 4;
  constexpr int CP = C + 1;                 // LDS pad: conflict-free col reads
  __shared__ float s[64 * CP];
  const int b = blockIdx.y;
  const int n0 = blockIdx.x * 64;
  const int tid = threadIdx.x;

  for (int v = tid; v < 64 * C; v += 256) {
    int r = v / C, c = v % C;
    s[r * CP + c] = X[(size_t)(b * NPTS + n0 + r) * S + coff + c];
  }
  __syncthreads();

  if (tid < 64) {
    float sum = 0.f;
    const float* row = &s[tid * CP];
#pragma unroll
    for (int c4 = 0; c4 < C4; ++c4) {
      float vx = row[4 * c4 + 0], vy = row[4 * c4 + 1];
      float vz = row[4 * c4 + 2], vw = row[4 * c4 + 3];
      sum = fmaf(vx, vx, sum); sum = fmaf(vy, vy, sum);
      sum = fmaf(vz, vz, sum); sum = fmaf(vw, vw, sum);
    }
    nrm[b * NPTS + n0 + tid] = sum;
  }

  for (int v = tid; v < 64 * C4; v += 256) {
    int c4 = v >> 6, jn = v & 63;
    const float* row = &s[jn * CP + 4 * c4];
    XT[((size_t)b * C4 + c4) * NPTS + n0 + jn] =
        make_float4(row[0], row[1], row[2], row[3]);
  }
}

// ---------------------------------------------------------------------------
// KNN: for each row i, indices of the 20 smallest (xx_j - (2*dot - xx_i)),
// ties broken by smaller j (== jax.lax.top_k stable semantics on -dist^2).
// Block = 256 thr (4 waves), 16 rows, wave w owns rows [4w,4w+4).
//
// v12 = v11 + (a) explicit 2-stage software pipeline on the c4-chunk loop
// (ping-pong NAMED register sets; `unroll 1` otherwise forbids the compiler
// from hoisting loads across iterations, so each chunk serialized
// load->wait(~250cy L2)->FMA and 3.5 waves/SIMD couldn't cover it -- the
// v10/v11 null-result signature: no pipe saturated, wall unmoved);
// (b) selection threshold lp[KNN-1] cached in REGISTERS per row (wave owns
// its rows exclusively; thr changes only on insert) -- deletes 8 dependent
// ~120cy LDS broadcast reads per tile; (c) s_ni hoisted to regs.
// __launch_bounds__(256,4) -> 128-VGPR cap so the ~123-reg body stays
// resident (v11's 64-reg codegen consumed loads immediately = no pipeline).
// Accumulation order per row (ascending c4, x/y/z/w), nj, key packing,
// insertion semantics unchanged -> bitwise-identical neighbor sets.
// ---------------------------------------------------------------------------
template <int C>
__global__ __launch_bounds__(256, 4) void k_knn(const float* __restrict__ Xrow,
                                                const float4* __restrict__ XT,
                                                const float* __restrict__ nrm,
                                                int S, int coff,
                                                int* __restrict__ idxout) {
  constexpr int C4 = C / 4;
  constexpr int CH = (C4 < 4) ? C4 : 4;      // c4 chunk size
  constexpr int ROWS = 16;                   // i-rows per block, 4 per wave
  __shared__ __align__(16) float s_xi[ROWS * C];
  __shared__ float s_ni[ROWS];
  __shared__ unsigned long long s_list[ROWS * KNN];

  const int b = blockIdx.y;
  const int rowbase = blockIdx.x * ROWS;
  const int tid = threadIdx.x, wave = tid >> 6, lane = tid & 63;

  for (int v = tid; v < ROWS * KNN; v += 256) s_list[v] = ~0ull;
  for (int v = tid; v < ROWS * C; v += 256) {
    int r = v / C, c = v % C;
    s_xi[v] = Xrow[(size_t)(b * NPTS + rowbase + r) * S + coff + c];
  }
  if (tid < ROWS) s_ni[tid] = nrm[b * NPTS + rowbase + tid];
  __syncthreads();

  const int r0 = wave * 4;
  const float4* xbase = XT + (size_t)b * C4 * NPTS;

  float ni[4];
#pragma unroll
  for (int r = 0; r < 4; ++r) ni[r] = s_ni[r0 + r];

  unsigned long long thr[4];                 // cached lp[KNN-1] per row
#pragma unroll
  for (int r = 0; r < 4; ++r) thr[r] = ~0ull;

  // exact top-20 insert; thr kept coherent in a register (wave-uniform)
  auto insert = [&](unsigned long long key, unsigned long long* lp,
                    unsigned long long& th) {
    unsigned long long mask = __ballot(key < th);
    while (mask) {
      int src = __ffsll((long long)mask) - 1;
      unsigned long long ck = __shfl(key, src);
      unsigned long long e = (lane < KNN) ? lp[lane] : ~0ull;
      unsigned long long ep = __shfl_up(e, 1);
      bool cc2 = ck < e;
      bool cp = (lane > 0) && (ck < ep);
      unsigned long long ne = cp ? ep : (cc2 ? ck : e);
      if (lane < KNN) lp[lane] = ne;
      th = __shfl(ne, KNN - 1);
      if (lane == src) key = ~0ull;   // consumed
      mask = __ballot(key < th);
    }
  };

  for (int jt = 0; jt < NPTS; jt += 128) {
    const int jA = jt + lane;
    const int jB = jt + 64 + lane;
    const float njA = nrm[b * NPTS + jA];
    const float njB = nrm[b * NPTS + jB];
    const float4* pA = xbase + jA;
    const float4* pB = xbase + jB;

    float aA[4][4], aB[4][4];
#pragma unroll
    for (int r = 0; r < 4; ++r) {
      aA[r][0] = aA[r][1] = aA[r][2] = aA[r][3] = 0.f;
      aB[r][0] = aB[r][1] = aB[r][2] = aB[r][3] = 0.f;
    }

    if constexpr (C4 >= 2 * CH) {
      // ---- 2-stage pipelined chunk loop: sets 0/1 ping-pong ----
      float4 sA0[CH], sB0[CH], sA1[CH], sB1[CH];
#pragma unroll
      for (int u = 0; u < CH; ++u) {         // prologue: chunk 0 -> set0
        sA0[u] = pA[(size_t)u * NPTS];
        sB0[u] = pB[(size_t)u * NPTS];
      }
#pragma unroll 1
      for (int cc = 0; cc < C4; cc += 2 * CH) {
        const int n1 = cc + CH;
        const int n2 = (cc + 2 * CH < C4) ? cc + 2 * CH : 0;  // wrap: dummy
        // issue chunk n1 -> set1 (consumed after FMA(set0), ~256 cyc away)
#pragma unroll
        for (int u = 0; u < CH; ++u) {
          sA1[u] = pA[(size_t)(n1 + u) * NPTS];
          sB1[u] = pB[(size_t)(n1 + u) * NPTS];
        }
        // FMA chunk cc from set0
#pragma unroll
        for (int u = 0; u < CH; ++u) {
#pragma unroll
          for (int r = 0; r < 4; ++r) {
            float4 v = *reinterpret_cast<const float4*>(
                &s_xi[(r0 + r) * C + 4 * (cc + u)]);   // wave-uniform bcast
            aA[r][0] = fmaf(v.x, sA0[u].x, aA[r][0]);
            aA[r][1] = fmaf(v.y, sA0[u].y, aA[r][1]);
            aA[r][2] = fmaf(v.z, sA0[u].z, aA[r][2]);
            aA[r][3] = fmaf(v.w, sA0[u].w, aA[r][3]);
            aB[r][0] = fmaf(v.x, sB0[u].x, aB[r][0]);
            aB[r][1] = fmaf(v.y, sB0[u].y, aB[r][1]);
            aB[r][2] = fmaf(v.z, sB0[u].z, aB[r][2]);
            aB[r][3] = fmaf(v.w, sB0[u].w, aB[r][3]);
          }
        }
        // issue chunk n2 -> set0 (next iteration's even chunk)
#pragma unroll
        for (int u = 0; u < CH; ++u) {
          sA0[u] = pA[(size_t)(n2 + u) * NPTS];
          sB0[u] = pB[(size_t)(n2 + u) * NPTS];
        }
        // FMA chunk n1 from set1
#pragma unroll
        for (int u = 0; u < CH; ++u) {
#pragma unroll
          for (int r = 0; r < 4; ++r) {
            float4 v = *reinterpret_cast<const float4*>(
                &s_xi[(r0 + r) * C + 4 * (n1 + u)]);
            aA[r][0] = fmaf(v.x, sA1[u].x, aA[r][0]);
            aA[r][1] = fmaf(v.y, sA1[u].y, aA[r][1]);
            aA[r][2] = fmaf(v.z, sA1[u].z, aA[r][2]);
            aA[r][3] = fmaf(v.w, sA1[u].w, aA[r][3]);
            aB[r][0] = fmaf(v.x, sB1[u].x, aB[r][0]);
            aB[r][1] = fmaf(v.y, sB1[u].y, aB[r][1]);
            aB[r][2] = fmaf(v.z, sB1[u].z, aB[r][2]);
            aB[r][3] = fmaf(v.w, sB1[u].w, aB[r][3]);
          }
        }
      }
    } else {
      // C=4 (C4==1): single chunk, no pipeline needed
      float4 xjA = pA[0];
      float4 xjB = pB[0];
#pragma unroll
      for (int r = 0; r < 4; ++r) {
        float4 v = *reinterpret_cast<const float4*>(&s_xi[(r0 + r) * C]);
        aA[r][0] = fmaf(v.x, xjA.x, aA[r][0]);
        aA[r][1] = fmaf(v.y, xjA.y, aA[r][1]);
        aA[r][2] = fmaf(v.z, xjA.z, aA[r][2]);
        aA[r][3] = fmaf(v.w, xjA.w, aA[r][3]);
        aB[r][0] = fmaf(v.x, xjB.x, aB[r][0]);
        aB[r][1] = fmaf(v.y, xjB.y, aB[r][1]);
        aB[r][2] = fmaf(v.z, xjB.z, aB[r][2]);
        aB[r][3] = fmaf(v.w, xjB.w, aB[r][3]);
      }
    }

#pragma unroll
    for (int r = 0; r < 4; ++r) {
      unsigned long long* lp = &s_list[(r0 + r) * KNN];
      {
        float dot = (aA[r][0] + aA[r][1]) + (aA[r][2] + aA[r][3]);
        float t2 = fmaf(2.f, dot, -ni[r]);   // (-xx_i + 2*dot), ref order
        float d = njA - t2;                  // ascending d == desc pd
        unsigned u = __float_as_uint(d);
        u ^= (unsigned)(((int)u) >> 31) | 0x80000000u;   // orderable float
        insert(((unsigned long long)u << 32) | (unsigned)jA, lp, thr[r]);
      }
      {
        float dot = (aB[r][0] + aB[r][1]) + (aB[r][2] + aB[r][3]);
        float t2 = fmaf(2.f, dot, -ni[r]);
        float d = njB - t2;
        unsigned u = __float_as_uint(d);
        u ^= (unsigned)(((int)u) >> 31) | 0x80000000u;
        insert(((unsigned long long)u << 32) | (unsigned)jB, lp, thr[r]);
      }
    }
  }

  // each wave owns its rows' lists: write indices (order within k irrelevant)
  if (lane < KNN) {
#pragma unroll
    for (int r = 0; r < 4; ++r)
      idxout[(size_t)(b * NPTS + rowbase + r0 + r) * KNN + lane] =
          (int)(s_list[(r0 + r) * KNN + lane] & 0xffffffffull);
  }
}

// ---------------------------------------------------------------------------
// per-point GEMM: Y[b,n,o] = sum_c A[o*C+c] * X[(b*N+n)*S+coff+c]
// 64 pts x 64 outs per block, K-chunks of 16 staged in LDS, 4x4 per thread.
// ---------------------------------------------------------------------------
__global__ __launch_bounds__(256) void k_gemm(const float* __restrict__ A,
                                              const float* __restrict__ X,
                                              float* __restrict__ Y,
                                              int S, int coff, int C, int O2) {
  __shared__ __align__(16) float sX[16 * 68];
  __shared__ __align__(16) float sA[16 * 68];
  const int b = blockIdx.z;
  const int nb = blockIdx.x * 64;
  const int ob = blockIdx.y * 64;
  const int tid = threadIdx.x, ty = tid >> 4, tx = tid & 15;
  float acc[4][4] = {};

  for (int kc = 0; kc < C; kc += 16) {
#pragma unroll
    for (int t = 0; t < 4; ++t) {
      int v = tid + t * 256;
      int p = v >> 4, k = v & 15;
      float xv = 0.f, av = 0.f;
      if (kc + k < C) {
        xv = X[(size_t)(b * NPTS + nb + p) * S + coff + kc + k];
        av = A[(size_t)(ob + p) * C + kc + k];
      }
      sX[k * 68 + p] = xv;
      sA[k * 68 + p] = av;
    }
    __syncthreads();
#pragma unroll
    for (int kk = 0; kk < 16; ++kk) {
      float4 xa = *reinterpret_cast<const float4*>(&sX[kk * 68 + ty * 4]);
      float4 wb = *reinterpret_cast<const float4*>(&sA[kk * 68 + tx * 4]);
      acc[0][0] = fmaf(xa.x, wb.x, acc[0][0]);
      acc[0][1] = fmaf(xa.x, wb.y, acc[0][1]);
      acc[0][2] = fmaf(xa.x, wb.z, acc[0][2]);
      acc[0][3] = fmaf(xa.x, wb.w, acc[0][3]);
      acc[1][0] = fmaf(xa.y, wb.x, acc[1][0]);
      acc[1][1] = fmaf(xa.y, wb.y, acc[1][1]);
      acc[1][2] = fmaf(xa.y, wb.z, acc[1][2]);
      acc[1][3] = fmaf(xa.y, wb.w, acc[1][3]);
      acc[2][0] = fmaf(xa.z, wb.x, acc[2][0]);
      acc[2][1] = fmaf(xa.z, wb.y, acc[2][1]);
      acc[2][2] = fmaf(xa.z, wb.z, acc[2][2]);
      acc[2][3] = fmaf(xa.z, wb.w, acc[2][3]);
      acc[3][0] = fmaf(xa.w, wb.x, acc[3][0]);
      acc[3][1] = fmaf(xa.w, wb.y, acc[3][1]);
      acc[3][2] = fmaf(xa.w, wb.z, acc[3][2]);
      acc[3][3] = fmaf(xa.w, wb.w, acc[3][3]);
    }
    __syncthreads();
  }
#pragma unroll
  for (int i = 0; i < 4; ++i) {
    float4 st = make_float4(acc[i][0], acc[i][1], acc[i][2], acc[i][3]);
    *reinterpret_cast<float4*>(
        &Y[(size_t)(b * NPTS + nb + ty * 4 + i) * O2 + ob + tx * 4]) = st;
  }
}

// ---------------------------------------------------------------------------
// gather + max-over-k + BN + LeakyReLU (monotone fold):
// out = leaky(a * ((a>=0 ? max_k : min_k) U[idx_k] + V[n]) + cbias)
// UV layout [B,N,2O]: U at [..,0..O), V at [..,O..2O). Writes Xcat slice.
// ---------------------------------------------------------------------------
__global__ __launch_bounds__(256) void k_gather(const float* __restrict__ UV,
                                                const int* __restrict__ idx,
                                                const float* __restrict__ bn,
                                                float* __restrict__ Xcat,
                                                int O2, int O, int coff_out) {
  const int b = blockIdx.z;
  const int og = blockIdx.y * 64;
  const int wave = threadIdx.x >> 6, lane = threadIdx.x & 63;
  const int n = blockIdx.x * 4 + wave;
  const int o = og + lane;
  const int* ip = &idx[(size_t)(b * NPTS + n) * KNN];
  float g = bn[o], be = bn[O + o], mu = bn[2 * O + o], va = bn[3 * O + o];
  float a = g / sqrtf(va + BN_EPS);
  float cb = be - mu * a;
  float vmax = -3.4e38f, vmin = 3.4e38f;
#pragma unroll
  for (int k = 0; k < KNN; ++k) {
    int jn = ip[k];
    float v = UV[(size_t)(b * NPTS + jn) * O2 + o];
    vmax = fmaxf(vmax, v);
    vmin = fminf(vmin, v);
  }
  float Vc = UV[(size_t)(b * NPTS + n) * O2 + O + o];
  float M = ((a >= 0.f) ? vmax : vmin) + Vc;
  float z = fmaf(a, M, cb);
  Xcat[(size_t)(b * NPTS + n) * 512 + coff_out + o] = fmaxf(z, 0.2f * z);
}

// ---------------------------------------------------------------------------
// final BN + leaky + transpose [B,N,512] -> [B,512,N]
// ---------------------------------------------------------------------------
__global__ __launch_bounds__(256) void k_out(const float* __restrict__ Y,
                                             const float* __restrict__ bn,
                                             float* __restrict__ out) {
  int n = blockIdx.x * 256 + threadIdx.x;
  int o = blockIdx.y;
  int b = blockIdx.z;
  float g = bn[o], be = bn[512 + o], mu = bn[1024 + o], va = bn[1536 + o];
  float a = g / sqrtf(va + BN_EPS);
  float cb = be - mu * a;
  float y = Y[(size_t)(b * NPTS + n) * 512 + o];
  float z = fmaf(a, y, cb);
  out[(size_t)(b * 512 + o) * NPTS + n] = fmaxf(z, 0.2f * z);
}

// ---------------------------------------------------------------------------
extern "C" void kernel_launch(void* const* d_in, const int* in_sizes, int n_in,
                              void* d_out, int out_size, void* d_ws,
                              size_t ws_size, hipStream_t stream) {
  const float* x  = (const float*)d_in[0];
  const float* W1 = (const float*)d_in[1];
  const float* W2 = (const float*)d_in[2];
  const float* W3 = (const float*)d_in[3];
  const float* W4 = (const float*)d_in[4];
  const float* W5 = (const float*)d_in[5];
  const float* bn1 = (const float*)d_in[6];
  const float* bn2 = (const float*)d_in[7];
  const float* bn3 = (const float*)d_in[8];
  const float* bn4 = (const float*)d_in[9];
  const float* bn5 = (const float*)d_in[10];
  float* out = (float*)d_out;

  // workspace layout (floats); total ~17.3M floats (~69 MB)
  float* f    = (float*)d_ws;
  float* xt   = f;                        // [B,N,4]        65536
  float* nrm  = f + 65536;                // [B,N]          16384
  int*   idx  = (int*)(f + 81920);        // [B,N,20] int   327680
  float* Xcat = f + 409600;               // [B,N,512]      8388608
  float* UV   = f + 8798208;              // [B,N,512] max  8388608
  float* A2   = f + 17186816;             // [512,128] max  65536

  // XT4 (channel-block-major xj operand) aliases UV: k_tr/k_knn use it
  // strictly BEFORE k_gemm overwrites UV in each stage (stream-ordered).
  float4* XT = (float4*)UV;

  k_xt<<<64, 256, 0, stream>>>(x, xt, nrm);

  // ---- EdgeConv 1: C=3(pad 4), O=64 ----  (xt IS XT4 for C=4)
  k_prep<<<1, 256, 0, stream>>>(W1, A2, 64, 3, 4);
  k_knn<4><<<dim3(512, 2), 256, 0, stream>>>(xt, (const float4*)xt, nrm, 4, 0, idx);
  k_gemm<<<dim3(128, 2, 2), 256, 0, stream>>>(A2, xt, UV, 4, 0, 4, 128);
  k_gather<<<dim3(2048, 1, 2), 256, 0, stream>>>(UV, idx, bn1, Xcat, 128, 64, 0);

  // ---- EdgeConv 2: C=64, O=64 ----
  k_tr<64><<<dim3(128, 2), 256, 0, stream>>>(Xcat, 512, 0, XT, nrm);
  k_prep<<<16, 256, 0, stream>>>(W2, A2, 64, 64, 64);
  k_knn<64><<<dim3(512, 2), 256, 0, stream>>>(Xcat, XT, nrm, 512, 0, idx);
  k_gemm<<<dim3(128, 2, 2), 256, 0, stream>>>(A2, Xcat, UV, 512, 0, 64, 128);
  k_gather<<<dim3(2048, 1, 2), 256, 0, stream>>>(UV, idx, bn2, Xcat, 128, 64, 64);

  // ---- EdgeConv 3: C=64, O=128 ----
  k_tr<64><<<dim3(128, 2), 256, 0, stream>>>(Xcat, 512, 64, XT, nrm);
  k_prep<<<32, 256, 0, stream>>>(W3, A2, 128, 64, 64);
  k_knn<64><<<dim3(512, 2), 256, 0, stream>>>(Xcat, XT, nrm, 512, 64, idx);
  k_gemm<<<dim3(128, 4, 2), 256, 0, stream>>>(A2, Xcat, UV, 512, 64, 64, 256);
  k_gather<<<dim3(2048, 2, 2), 256, 0, stream>>>(UV, idx, bn3, Xcat, 256, 128, 128);

  // ---- EdgeConv 4: C=128, O=256 ----
  k_tr<128><<<dim3(128, 2), 256, 0, stream>>>(Xcat, 512, 128, XT, nrm);
  k_prep<<<128, 256, 0, stream>>>(W4, A2, 256, 128, 128);
  k_knn<128><<<dim3(512, 2), 256, 0, stream>>>(Xcat, XT, nrm, 512, 128, idx);
  k_gemm<<<dim3(128, 8, 2), 256, 0, stream>>>(A2, Xcat, UV, 512, 128, 128, 512);
  k_gather<<<dim3(2048, 4, 2), 256, 0, stream>>>(UV, idx, bn4, Xcat, 512, 256, 256);

  // ---- conv5 + BN + leaky, output [B,512,N] ----
  k_gemm<<<dim3(128, 8, 2), 256, 0, stream>>>(W5, Xcat, UV, 512, 0, 512, 512);
  k_out<<<dim3(32, 512, 2), 256, 0, stream>>>(UV, bn5, out);
}

// Round 13
// 3252.647 us; speedup vs baseline: 2.0593x; 2.0593x over previous
//
#include <hip/hip_runtime.h>
#include <stdint.h>

#define NPTS 8192
#define BATCH 2
#define KNN 20
#define BN_EPS 1e-5f

// ---------------------------------------------------------------------------
// transpose x [B,3,N] -> xt [B,N,4] (pad 4th chan with 0) + squared norms
// (xt doubles as the channel-block-major XT4 for C=4: XT4[b][0][n] = xt[b][n])
// ---------------------------------------------------------------------------
__global__ __launch_bounds__(256) void k_xt(const float* __restrict__ x,
                                            float* __restrict__ xt,
                                            float* __restrict__ nrm) {
  int i = blockIdx.x * 256 + threadIdx.x;          // over B*N
  int b = i / NPTS, n = i % NPTS;
  float x0 = x[((size_t)b * 3 + 0) * NPTS + n];
  float x1 = x[((size_t)b * 3 + 1) * NPTS + n];
  float x2 = x[((size_t)b * 3 + 2) * NPTS + n];
  float4 v = make_float4(x0, x1, x2, 0.f);
  reinterpret_cast<float4*>(xt)[i] = v;
  // mimic np.sum(x*x) order: ((x0^2 + x1^2) + x2^2), no fma
  float s0 = x0 * x0, s1 = x1 * x1, s2 = x2 * x2;
  nrm[i] = (s0 + s1) + s2;
}

// ---------------------------------------------------------------------------
// build stacked weights A2[2O][Cpad]: rows 0..O-1 = Wn, rows O..2O-1 = Wc-Wn
// (zero-pad c >= Creal; W is [O][2*Creal] row-major)
// ---------------------------------------------------------------------------
__global__ __launch_bounds__(256) void k_prep(const float* __restrict__ W,
                                              float* __restrict__ A2,
                                              int O, int Creal, int Cpad) {
  int i = blockIdx.x * 256 + threadIdx.x;
  if (i >= O * Cpad) return;
  int o = i / Cpad, c = i % Cpad;
  float wn = (c < Creal) ? W[(size_t)o * 2 * Creal + c] : 0.f;
  float wc = (c < Creal) ? W[(size_t)o * 2 * Creal + Creal + c] : 0.f;
  A2[(size_t)o * Cpad + c] = wn;
  A2[(size_t)(O + o) * Cpad + c] = wc - wn;
}

// ---------------------------------------------------------------------------
// transpose a channel slice of Xcat to channel-block-major XT4[b][c4][n]
// (float4 = channels 4c4..4c4+3 of point n) AND compute squared norms
// (replaces k_norms; same fmaf order -> bitwise-identical nrm).
// Block: 64 points.  Row reads coalesced; XT writes coalesced (1 KB/instr).
// ---------------------------------------------------------------------------
template <int C>
__global__ __launch_bounds__(256) void k_tr(const float* __restrict__ X,
                                            int S, int coff,
                                            float4* __restrict__ XT,
                                            float* __restrict__ nrm) {
  constexpr int C4 = C / 4;
  constexpr int CP = C + 1;                 // LDS pad: conflict-free col reads
  __shared__ float s[64 * CP];
  const int b = blockIdx.y;
  const int n0 = blockIdx.x * 64;
  const int tid = threadIdx.x;

  for (int v = tid; v < 64 * C; v += 256) {
    int r = v / C, c = v % C;
    s[r * CP + c] = X[(size_t)(b * NPTS + n0 + r) * S + coff + c];
  }
  __syncthreads();

  if (tid < 64) {
    float sum = 0.f;
    const float* row = &s[tid * CP];
#pragma unroll
    for (int c4 = 0; c4 < C4; ++c4) {
      float vx = row[4 * c4 + 0], vy = row[4 * c4 + 1];
      float vz = row[4 * c4 + 2], vw = row[4 * c4 + 3];
      sum = fmaf(vx, vx, sum); sum = fmaf(vy, vy, sum);
      sum = fmaf(vz, vz, sum); sum = fmaf(vw, vw, sum);
    }
    nrm[b * NPTS + n0 + tid] = sum;
  }

  for (int v = tid; v < 64 * C4; v += 256) {
    int c4 = v >> 6, jn = v & 63;
    const float* row = &s[jn * CP + 4 * c4];
    XT[((size_t)b * C4 + c4) * NPTS + n0 + jn] =
        make_float4(row[0], row[1], row[2], row[3]);
  }
}

// ---------------------------------------------------------------------------
// KNN partial pass: for each row i, the sorted top-20 (dist,j) u64 keys over
// this block's j-range.  Grid: (NPTS/32 rowgroups, NSPLIT j-ranges, B).
// Block = 256 thr (4 waves), 32 rows, wave w owns rows [8w,8w+8).
//
// v13 model [from v8/v10/v11 nulls]: the kNN wall is an L3/LLC bandwidth
// ceiling ~15.6 TB/s; perf = BW x (rows-per-wave)/2 FLOP/byte.  v11 had
// R=4 -> 32 TF (measured exactly).  This kernel sets R=8 (v7's PROVEN
// 60-VGPR no-spill codegen: acc[8][4], CH=4, unroll-1 chunk loop) and
// recovers occupancy via the j-range split PROVEN in v10 (NSPLIT=2 ->
// 1024 blocks = 4 blk/CU, partial sorted-20 lists merged exactly by
// k_merge).  Traffic halves (2.1 GB), FMA count unchanged.  v12's
// ping-pong reg pipeline is reverted (3rd allocator-spill strike: the
// compiler pins 64 VGPR and spills named sets; never again).
// Per-(i,j) distance math bit-identical to v7/v8/v10/v11.
// ---------------------------------------------------------------------------
template <int C>
__global__ __launch_bounds__(256) void k_knn(const float* __restrict__ Xrow,
                                             const float4* __restrict__ XT,
                                             const float* __restrict__ nrm,
                                             int S, int coff,
                                             unsigned long long* __restrict__ kout) {
  constexpr int C4 = C / 4;
  constexpr int CH = (C4 < 4) ? C4 : 4;      // c4 chunk size
  constexpr int ROWS = 32;                   // i-rows per block, 8 per wave
  __shared__ __align__(16) float s_xi[ROWS * C];
  __shared__ float s_ni[ROWS];
  __shared__ unsigned long long s_list[ROWS * KNN];

  const int b = blockIdx.z;
  const int rowbase = blockIdx.x * ROWS;
  const int tid = threadIdx.x, wave = tid >> 6, lane = tid & 63;
  const int nsp = gridDim.y;
  const int jspan = NPTS / nsp;
  const int jbase = blockIdx.y * jspan;

  for (int v = tid; v < ROWS * KNN; v += 256) s_list[v] = ~0ull;
  for (int v = tid; v < ROWS * C; v += 256) {
    int r = v / C, c = v % C;
    s_xi[v] = Xrow[(size_t)(b * NPTS + rowbase + r) * S + coff + c];
  }
  if (tid < ROWS) s_ni[tid] = nrm[b * NPTS + rowbase + tid];
  __syncthreads();

  const int r0 = wave * 8;
  const float4* xbase = XT + (size_t)b * C4 * NPTS;

  for (int jt = jbase; jt < jbase + jspan; jt += 64) {
    const int j = jt + lane;
    const float nj = nrm[b * NPTS + j];

    float a[8][4];
#pragma unroll
    for (int r = 0; r < 8; ++r)
      a[r][0] = a[r][1] = a[r][2] = a[r][3] = 0.f;

#pragma unroll 1
    for (int cc = 0; cc < C4; cc += CH) {
      float4 xj[CH];
#pragma unroll
      for (int u = 0; u < CH; ++u)
        xj[u] = xbase[(size_t)(cc + u) * NPTS + j];     // coalesced 1 KB/instr
#pragma unroll
      for (int u = 0; u < CH; ++u) {
#pragma unroll
        for (int r = 0; r < 8; ++r) {
          float4 v = *reinterpret_cast<const float4*>(
              &s_xi[(r0 + r) * C + 4 * (cc + u)]);      // wave-uniform bcast
          a[r][0] = fmaf(v.x, xj[u].x, a[r][0]);
          a[r][1] = fmaf(v.y, xj[u].y, a[r][1]);
          a[r][2] = fmaf(v.z, xj[u].z, a[r][2]);
          a[r][3] = fmaf(v.w, xj[u].w, a[r][3]);
        }
      }
    }

#pragma unroll
    for (int r = 0; r < 8; ++r) {
      float dot = (a[r][0] + a[r][1]) + (a[r][2] + a[r][3]);
      float t2 = fmaf(2.f, dot, -s_ni[r0 + r]);    // (-xx_i + 2*dot), ref order
      float d = nj - t2;                           // ascending d == desc pd
      unsigned u = __float_as_uint(d);
      u ^= (unsigned)(((int)u) >> 31) | 0x80000000u;   // orderable float
      unsigned long long key = ((unsigned long long)u << 32) | (unsigned)j;

      unsigned long long* lp = &s_list[(r0 + r) * KNN];
      unsigned long long thr = lp[KNN - 1];            // broadcast read
      unsigned long long mask = __ballot(key < thr);
      while (mask) {
        int src = __ffsll((long long)mask) - 1;
        unsigned long long ck = __shfl(key, src);
        unsigned long long e = (lane < KNN) ? lp[lane] : ~0ull;
        unsigned long long ep = __shfl_up(e, 1);
        bool cc2 = ck < e;
        bool cp = (lane > 0) && (ck < ep);
        unsigned long long ne = cp ? ep : (cc2 ? ck : e);
        if (lane < KNN) lp[lane] = ne;
        thr = __shfl(ne, KNN - 1);
        if (lane == src) key = ~0ull;   // consumed
        mask = __ballot(key < thr);
      }
    }
  }

  // write this j-range's sorted 20-key list per row
  if (lane < KNN) {
#pragma unroll
    for (int r = 0; r < 8; ++r)
      kout[((size_t)(b * NPTS + rowbase + r0 + r) * nsp + blockIdx.y) * KNN +
           lane] = s_list[(r0 + r) * KNN + lane];
  }
}

// ---------------------------------------------------------------------------
// merge <=2 sorted 20-key lists per row -> final 20 neighbor indices.
// Exact: global top-20 = 20 smallest keys of the union (keys globally
// ordered, unique j per key, halves disjoint).  (Proven on HW in v10.)
// ---------------------------------------------------------------------------
__global__ __launch_bounds__(256) void k_merge(
    const unsigned long long* __restrict__ kbuf, int nsplit,
    int* __restrict__ idxout) {
  int row = blockIdx.x * 256 + threadIdx.x;       // over B*NPTS
  const unsigned long long* kp = kbuf + (size_t)row * nsplit * KNN;
  int* op = idxout + (size_t)row * KNN;
  int p0 = 0, p1 = 0;
#pragma unroll
  for (int k = 0; k < KNN; ++k) {
    unsigned long long v0 = (p0 < KNN) ? kp[p0] : ~0ull;
    unsigned long long v1 =
        (nsplit > 1 && p1 < KNN) ? kp[KNN + p1] : ~0ull;
    bool t0 = v0 <= v1;
    op[k] = (int)((t0 ? v0 : v1) & 0xffffffffull);
    p0 += t0 ? 1 : 0;
    p1 += t0 ? 0 : 1;
  }
}

// ---------------------------------------------------------------------------
// per-point GEMM: Y[b,n,o] = sum_c A[o*C+c] * X[(b*N+n)*S+coff+c]
// 64 pts x 64 outs per block, K-chunks of 16 staged in LDS, 4x4 per thread.
// ---------------------------------------------------------------------------
__global__ __launch_bounds__(256) void k_gemm(const float* __restrict__ A,
                                              const float* __restrict__ X,
                                              float* __restrict__ Y,
                                              int S, int coff, int C, int O2) {
  __shared__ __align__(16) float sX[16 * 68];
  __shared__ __align__(16) float sA[16 * 68];
  const int b = blockIdx.z;
  const int nb = blockIdx.x * 64;
  const int ob = blockIdx.y * 64;
  const int tid = threadIdx.x, ty = tid >> 4, tx = tid & 15;
  float acc[4][4] = {};

  for (int kc = 0; kc < C; kc += 16) {
#pragma unroll
    for (int t = 0; t < 4; ++t) {
      int v = tid + t * 256;
      int p = v >> 4, k = v & 15;
      float xv = 0.f, av = 0.f;
      if (kc + k < C) {
        xv = X[(size_t)(b * NPTS + nb + p) * S + coff + kc + k];
        av = A[(size_t)(ob + p) * C + kc + k];
      }
      sX[k * 68 + p] = xv;
      sA[k * 68 + p] = av;
    }
    __syncthreads();
#pragma unroll
    for (int kk = 0; kk < 16; ++kk) {
      float4 xa = *reinterpret_cast<const float4*>(&sX[kk * 68 + ty * 4]);
      float4 wb = *reinterpret_cast<const float4*>(&sA[kk * 68 + tx * 4]);
      acc[0][0] = fmaf(xa.x, wb.x, acc[0][0]);
      acc[0][1] = fmaf(xa.x, wb.y, acc[0][1]);
      acc[0][2] = fmaf(xa.x, wb.z, acc[0][2]);
      acc[0][3] = fmaf(xa.x, wb.w, acc[0][3]);
      acc[1][0] = fmaf(xa.y, wb.x, acc[1][0]);
      acc[1][1] = fmaf(xa.y, wb.y, acc[1][1]);
      acc[1][2] = fmaf(xa.y, wb.z, acc[1][2]);
      acc[1][3] = fmaf(xa.y, wb.w, acc[1][3]);
      acc[2][0] = fmaf(xa.z, wb.x, acc[2][0]);
      acc[2][1] = fmaf(xa.z, wb.y, acc[2][1]);
      acc[2][2] = fmaf(xa.z, wb.z, acc[2][2]);
      acc[2][3] = fmaf(xa.z, wb.w, acc[2][3]);
      acc[3][0] = fmaf(xa.w, wb.x, acc[3][0]);
      acc[3][1] = fmaf(xa.w, wb.y, acc[3][1]);
      acc[3][2] = fmaf(xa.w, wb.z, acc[3][2]);
      acc[3][3] = fmaf(xa.w, wb.w, acc[3][3]);
    }
    __syncthreads();
  }
#pragma unroll
  for (int i = 0; i < 4; ++i) {
    float4 st = make_float4(acc[i][0], acc[i][1], acc[i][2], acc[i][3]);
    *reinterpret_cast<float4*>(
        &Y[(size_t)(b * NPTS + nb + ty * 4 + i) * O2 + ob + tx * 4]) = st;
  }
}

// ---------------------------------------------------------------------------
// gather + max-over-k + BN + LeakyReLU (monotone fold):
// out = leaky(a * ((a>=0 ? max_k : min_k) U[idx_k] + V[n]) + cbias)
// UV layout [B,N,2O]: U at [..,0..O), V at [..,O..2O). Writes Xcat slice.
// ---------------------------------------------------------------------------
__global__ __launch_bounds__(256) void k_gather(const float* __restrict__ UV,
                                                const int* __restrict__ idx,
                                                const float* __restrict__ bn,
                                                float* __restrict__ Xcat,
                                                int O2, int O, int coff_out) {
  const int b = blockIdx.z;
  const int og = blockIdx.y * 64;
  const int wave = threadIdx.x >> 6, lane = threadIdx.x & 63;
  const int n = blockIdx.x * 4 + wave;
  const int o = og + lane;
  const int* ip = &idx[(size_t)(b * NPTS + n) * KNN];
  float g = bn[o], be = bn[O + o], mu = bn[2 * O + o], va = bn[3 * O + o];
  float a = g / sqrtf(va + BN_EPS);
  float cb = be - mu * a;
  float vmax = -3.4e38f, vmin = 3.4e38f;
#pragma unroll
  for (int k = 0; k < KNN; ++k) {
    int jn = ip[k];
    float v = UV[(size_t)(b * NPTS + jn) * O2 + o];
    vmax = fmaxf(vmax, v);
    vmin = fminf(vmin, v);
  }
  float Vc = UV[(size_t)(b * NPTS + n) * O2 + O + o];
  float M = ((a >= 0.f) ? vmax : vmin) + Vc;
  float z = fmaf(a, M, cb);
  Xcat[(size_t)(b * NPTS + n) * 512 + coff_out + o] = fmaxf(z, 0.2f * z);
}

// ---------------------------------------------------------------------------
// final BN + leaky + transpose [B,N,512] -> [B,512,N]
// ---------------------------------------------------------------------------
__global__ __launch_bounds__(256) void k_out(const float* __restrict__ Y,
                                             const float* __restrict__ bn,
                                             float* __restrict__ out) {
  int n = blockIdx.x * 256 + threadIdx.x;
  int o = blockIdx.y;
  int b = blockIdx.z;
  float g = bn[o], be = bn[512 + o], mu = bn[1024 + o], va = bn[1536 + o];
  float a = g / sqrtf(va + BN_EPS);
  float cb = be - mu * a;
  float y = Y[(size_t)(b * NPTS + n) * 512 + o];
  float z = fmaf(a, y, cb);
  out[(size_t)(b * 512 + o) * NPTS + n] = fmaxf(z, 0.2f * z);
}

// ---------------------------------------------------------------------------
extern "C" void kernel_launch(void* const* d_in, const int* in_sizes, int n_in,
                              void* d_out, int out_size, void* d_ws,
                              size_t ws_size, hipStream_t stream) {
  const float* x  = (const float*)d_in[0];
  const float* W1 = (const float*)d_in[1];
  const float* W2 = (const float*)d_in[2];
  const float* W3 = (const float*)d_in[3];
  const float* W4 = (const float*)d_in[4];
  const float* W5 = (const float*)d_in[5];
  const float* bn1 = (const float*)d_in[6];
  const float* bn2 = (const float*)d_in[7];
  const float* bn3 = (const float*)d_in[8];
  const float* bn4 = (const float*)d_in[9];
  const float* bn5 = (const float*)d_in[10];
  float* out = (float*)d_out;

  // workspace layout (floats); total ~17.3M floats (~69 MB)
  float* f    = (float*)d_ws;
  float* xt   = f;                        // [B,N,4]        65536
  float* nrm  = f + 65536;                // [B,N]          16384
  int*   idx  = (int*)(f + 81920);        // [B,N,20] int   327680
  float* Xcat = f + 409600;               // [B,N,512]      8388608
  float* UV   = f + 8798208;              // [B,N,512] max  8388608
  float* A2   = f + 17186816;             // [512,128] max  65536

  // XT4 (channel-block-major xj operand) aliases UV[0 .. 2.1M floats];
  // kbuf (partial top-20 key lists) aliases UV[3.15M ..]: both are consumed
  // strictly BEFORE k_gemm overwrites UV in each stage (stream-ordered).
  float4* XT = (float4*)UV;
  unsigned long long* kbuf = (unsigned long long*)(UV + 3145728);

  k_xt<<<64, 256, 0, stream>>>(x, xt, nrm);

  // ---- EdgeConv 1: C=3(pad 4), O=64 ----  (xt IS XT4 for C=4)
  k_prep<<<1, 256, 0, stream>>>(W1, A2, 64, 3, 4);
  k_knn<4><<<dim3(256, 2, 2), 256, 0, stream>>>(xt, (const float4*)xt, nrm, 4, 0, kbuf);
  k_merge<<<64, 256, 0, stream>>>(kbuf, 2, idx);
  k_gemm<<<dim3(128, 2, 2), 256, 0, stream>>>(A2, xt, UV, 4, 0, 4, 128);
  k_gather<<<dim3(2048, 1, 2), 256, 0, stream>>>(UV, idx, bn1, Xcat, 128, 64, 0);

  // ---- EdgeConv 2: C=64, O=64 ----
  k_tr<64><<<dim3(128, 2), 256, 0, stream>>>(Xcat, 512, 0, XT, nrm);
  k_prep<<<16, 256, 0, stream>>>(W2, A2, 64, 64, 64);
  k_knn<64><<<dim3(256, 2, 2), 256, 0, stream>>>(Xcat, XT, nrm, 512, 0, kbuf);
  k_merge<<<64, 256, 0, stream>>>(kbuf, 2, idx);
  k_gemm<<<dim3(128, 2, 2), 256, 0, stream>>>(A2, Xcat, UV, 512, 0, 64, 128);
  k_gather<<<dim3(2048, 1, 2), 256, 0, stream>>>(UV, idx, bn2, Xcat, 128, 64, 64);

  // ---- EdgeConv 3: C=64, O=128 ----
  k_tr<64><<<dim3(128, 2), 256, 0, stream>>>(Xcat, 512, 64, XT, nrm);
  k_prep<<<32, 256, 0, stream>>>(W3, A2, 128, 64, 64);
  k_knn<64><<<dim3(256, 2, 2), 256, 0, stream>>>(Xcat, XT, nrm, 512, 64, kbuf);
  k_merge<<<64, 256, 0, stream>>>(kbuf, 2, idx);
  k_gemm<<<dim3(128, 4, 2), 256, 0, stream>>>(A2, Xcat, UV, 512, 64, 64, 256);
  k_gather<<<dim3(2048, 2, 2), 256, 0, stream>>>(UV, idx, bn3, Xcat, 256, 128, 128);

  // ---- EdgeConv 4: C=128, O=256 ----
  k_tr<128><<<dim3(128, 2), 256, 0, stream>>>(Xcat, 512, 128, XT, nrm);
  k_prep<<<128, 256, 0, stream>>>(W4, A2, 256, 128, 128);
  k_knn<128><<<dim3(256, 2, 2), 256, 0, stream>>>(Xcat, XT, nrm, 512, 128, kbuf);
  k_merge<<<64, 256, 0, stream>>>(kbuf, 2, idx);
  k_gemm<<<dim3(128, 8, 2), 256, 0, stream>>>(A2, Xcat, UV, 512, 128, 128, 512);
  k_gather<<<dim3(2048, 4, 2), 256, 0, stream>>>(UV, idx, bn4, Xcat, 512, 256, 256);

  // ---- conv5 + BN + leaky, output [B,512,N] ----
  k_gemm<<<dim3(128, 8, 2), 256, 0, stream>>>(W5, Xcat, UV, 512, 0, 512, 512);
  k_out<<<dim3(32, 512, 2), 256, 0, stream>>>(UV, bn5, out);
}

// Round 14
// 2675.903 us; speedup vs baseline: 2.5032x; 1.2155x over previous
//
#include <hip/hip_runtime.h>
#include <stdint.h>

#define NPTS 8192
#define BATCH 2
#define KNN 20
#define BN_EPS 1e-5f

// ---------------------------------------------------------------------------
// transpose x [B,3,N] -> xt [B,N,4] (pad 4th chan with 0) + squared norms
// (xt doubles as the channel-block-major XT4 for C=4: XT4[b][0][n] = xt[b][n])
// ---------------------------------------------------------------------------
__global__ __launch_bounds__(256) void k_xt(const float* __restrict__ x,
                                            float* __restrict__ xt,
                                            float* __restrict__ nrm) {
  int i = blockIdx.x * 256 + threadIdx.x;          // over B*N
  int b = i / NPTS, n = i % NPTS;
  float x0 = x[((size_t)b * 3 + 0) * NPTS + n];
  float x1 = x[((size_t)b * 3 + 1) * NPTS + n];
  float x2 = x[((size_t)b * 3 + 2) * NPTS + n];
  float4 v = make_float4(x0, x1, x2, 0.f);
  reinterpret_cast<float4*>(xt)[i] = v;
  // mimic np.sum(x*x) order: ((x0^2 + x1^2) + x2^2), no fma
  float s0 = x0 * x0, s1 = x1 * x1, s2 = x2 * x2;
  nrm[i] = (s0 + s1) + s2;
}

// ---------------------------------------------------------------------------
// build stacked weights A2[2O][Cpad]: rows 0..O-1 = Wn, rows O..2O-1 = Wc-Wn
// (zero-pad c >= Creal; W is [O][2*Creal] row-major)
// ---------------------------------------------------------------------------
__global__ __launch_bounds__(256) void k_prep(const float* __restrict__ W,
                                              float* __restrict__ A2,
                                              int O, int Creal, int Cpad) {
  int i = blockIdx.x * 256 + threadIdx.x;
  if (i >= O * Cpad) return;
  int o = i / Cpad, c = i % Cpad;
  float wn = (c < Creal) ? W[(size_t)o * 2 * Creal + c] : 0.f;
  float wc = (c < Creal) ? W[(size_t)o * 2 * Creal + Creal + c] : 0.f;
  A2[(size_t)o * Cpad + c] = wn;
  A2[(size_t)(O + o) * Cpad + c] = wc - wn;
}

// ---------------------------------------------------------------------------
// transpose a channel slice of Xcat to channel-block-major XT4[b][c4][n]
// (float4 = channels 4c4..4c4+3 of point n) AND compute squared norms
// (replaces k_norms; same fmaf order -> bitwise-identical nrm).
// Block: 64 points.  Row reads coalesced; XT writes coalesced (1 KB/instr).
// ---------------------------------------------------------------------------
template <int C>
__global__ __launch_bounds__(256) void k_tr(const float* __restrict__ X,
                                            int S, int coff,
                                            float4* __restrict__ XT,
                                            float* __restrict__ nrm) {
  constexpr int C4 = C / 4;
  constexpr int CP = C + 1;                 // LDS pad: conflict-free col reads
  __shared__ float s[64 * CP];
  const int b = blockIdx.y;
  const int n0 = blockIdx.x * 64;
  const int tid = threadIdx.x;

  for (int v = tid; v < 64 * C; v += 256) {
    int r = v / C, c = v % C;
    s[r * CP + c] = X[(size_t)(b * NPTS + n0 + r) * S + coff + c];
  }
  __syncthreads();

  if (tid < 64) {
    float sum = 0.f;
    const float* row = &s[tid * CP];
#pragma unroll
    for (int c4 = 0; c4 < C4; ++c4) {
      float vx = row[4 * c4 + 0], vy = row[4 * c4 + 1];
      float vz = row[4 * c4 + 2], vw = row[4 * c4 + 3];
      sum = fmaf(vx, vx, sum); sum = fmaf(vy, vy, sum);
      sum = fmaf(vz, vz, sum); sum = fmaf(vw, vw, sum);
    }
    nrm[b * NPTS + n0 + tid] = sum;
  }

  for (int v = tid; v < 64 * C4; v += 256) {
    int c4 = v >> 6, jn = v & 63;
    const float* row = &s[jn * CP + 4 * c4];
    XT[((size_t)b * C4 + c4) * NPTS + n0 + jn] =
        make_float4(row[0], row[1], row[2], row[3]);
  }
}

// ---------------------------------------------------------------------------
// KNN: for each row i, indices of the 20 smallest (xx_j - (2*dot - xx_i)),
// ties broken by smaller j (== jax.lax.top_k stable semantics on -dist^2).
// Block = 256 thr (4 waves), 16 rows, wave w owns rows [4w,4w+4).
//
// v14 = v11 body (best verified: JPL=2, R=4) + XCD batch-partition swizzle.
// Model [v8/v10/v11/v13 nulls]: the ~1100us knn<128> wall is invariant to
// wave count, LDS-op count, and total traffic -> shared constant is L2
// CAPACITY THRASH: both batches' XT4 (8 MB) stream through every XCD's
// 4 MB L2, so every xj load pays L3 latency (~500cy), and no schedule knob
// touches that.  Fix: 1D grid, block-ID swizzle so batch b's blocks land
// on XCDs {4b..4b+3} (wgid%8 round-robin heuristic): each XCD L2 then
// holds exactly one batch's 4 MB XT4.  Perf-only; correctness unaffected.
// wgid = (local>>2)*8 + b*4 + (local&3), local in [0,512) -- bijective.
// Distance math, key packing, selection identical to v11 -> same neighbors.
// ---------------------------------------------------------------------------
template <int C>
__global__ __launch_bounds__(256, 4) void k_knn(const float* __restrict__ Xrow,
                                                const float4* __restrict__ XT,
                                                const float* __restrict__ nrm,
                                                int S, int coff,
                                                int* __restrict__ idxout) {
  constexpr int C4 = C / 4;
  constexpr int CH = (C4 < 4) ? C4 : 4;      // c4 chunk size
  constexpr int ROWS = 16;                   // i-rows per block, 4 per wave
  __shared__ __align__(16) float s_xi[ROWS * C];
  __shared__ float s_ni[ROWS];
  __shared__ unsigned long long s_list[ROWS * KNN];

  // XCD batch-partition decode (1D grid of 1024 blocks)
  const int wgid = blockIdx.x;
  const int slot = wgid & 7;
  const int b = slot >> 2;                           // batch -> XCD group
  const int local = ((wgid >> 3) << 2) | (slot & 3); // [0,512) rowgroup
  const int rowbase = local * ROWS;
  const int tid = threadIdx.x, wave = tid >> 6, lane = tid & 63;

  for (int v = tid; v < ROWS * KNN; v += 256) s_list[v] = ~0ull;
  for (int v = tid; v < ROWS * C; v += 256) {
    int r = v / C, c = v % C;
    s_xi[v] = Xrow[(size_t)(b * NPTS + rowbase + r) * S + coff + c];
  }
  if (tid < ROWS) s_ni[tid] = nrm[b * NPTS + rowbase + tid];
  __syncthreads();

  const int r0 = wave * 4;
  const float4* xbase = XT + (size_t)b * C4 * NPTS;

  // exact top-20 insert of one candidate key into this row's sorted list
  auto insert = [&](unsigned long long key, unsigned long long* lp) {
    unsigned long long thr = lp[KNN - 1];            // broadcast read
    unsigned long long mask = __ballot(key < thr);
    while (mask) {
      int src = __ffsll((long long)mask) - 1;
      unsigned long long ck = __shfl(key, src);
      unsigned long long e = (lane < KNN) ? lp[lane] : ~0ull;
      unsigned long long ep = __shfl_up(e, 1);
      bool cc2 = ck < e;
      bool cp = (lane > 0) && (ck < ep);
      unsigned long long ne = cp ? ep : (cc2 ? ck : e);
      if (lane < KNN) lp[lane] = ne;
      thr = __shfl(ne, KNN - 1);
      if (lane == src) key = ~0ull;   // consumed
      mask = __ballot(key < thr);
    }
  };

  for (int jt = 0; jt < NPTS; jt += 128) {
    const int jA = jt + lane;
    const int jB = jt + 64 + lane;
    const float njA = nrm[b * NPTS + jA];
    const float njB = nrm[b * NPTS + jB];

    float aA[4][4], aB[4][4];
#pragma unroll
    for (int r = 0; r < 4; ++r) {
      aA[r][0] = aA[r][1] = aA[r][2] = aA[r][3] = 0.f;
      aB[r][0] = aB[r][1] = aB[r][2] = aB[r][3] = 0.f;
    }

#pragma unroll 1
    for (int cc = 0; cc < C4; cc += CH) {
      float4 xjA[CH], xjB[CH];
#pragma unroll
      for (int u = 0; u < CH; ++u)
        xjA[u] = xbase[(size_t)(cc + u) * NPTS + jA];   // coalesced 1 KB/instr
#pragma unroll
      for (int u = 0; u < CH; ++u)
        xjB[u] = xbase[(size_t)(cc + u) * NPTS + jB];
#pragma unroll
      for (int u = 0; u < CH; ++u) {
#pragma unroll
        for (int r = 0; r < 4; ++r) {
          float4 v = *reinterpret_cast<const float4*>(
              &s_xi[(r0 + r) * C + 4 * (cc + u)]);      // ONE bcast, 8 FMAs
          aA[r][0] = fmaf(v.x, xjA[u].x, aA[r][0]);
          aA[r][1] = fmaf(v.y, xjA[u].y, aA[r][1]);
          aA[r][2] = fmaf(v.z, xjA[u].z, aA[r][2]);
          aA[r][3] = fmaf(v.w, xjA[u].w, aA[r][3]);
          aB[r][0] = fmaf(v.x, xjB[u].x, aB[r][0]);
          aB[r][1] = fmaf(v.y, xjB[u].y, aB[r][1]);
          aB[r][2] = fmaf(v.z, xjB[u].z, aB[r][2]);
          aB[r][3] = fmaf(v.w, xjB[u].w, aB[r][3]);
        }
      }
    }

#pragma unroll
    for (int r = 0; r < 4; ++r) {
      unsigned long long* lp = &s_list[(r0 + r) * KNN];
      {
        float dot = (aA[r][0] + aA[r][1]) + (aA[r][2] + aA[r][3]);
        float t2 = fmaf(2.f, dot, -s_ni[r0 + r]);  // (-xx_i + 2*dot), ref order
        float d = njA - t2;                        // ascending d == desc pd
        unsigned u = __float_as_uint(d);
        u ^= (unsigned)(((int)u) >> 31) | 0x80000000u;   // orderable float
        insert(((unsigned long long)u << 32) | (unsigned)jA, lp);
      }
      {
        float dot = (aB[r][0] + aB[r][1]) + (aB[r][2] + aB[r][3]);
        float t2 = fmaf(2.f, dot, -s_ni[r0 + r]);
        float d = njB - t2;
        unsigned u = __float_as_uint(d);
        u ^= (unsigned)(((int)u) >> 31) | 0x80000000u;
        insert(((unsigned long long)u << 32) | (unsigned)jB, lp);
      }
    }
  }

  // each wave owns its rows' lists: write indices (order within k irrelevant)
  if (lane < KNN) {
#pragma unroll
    for (int r = 0; r < 4; ++r)
      idxout[(size_t)(b * NPTS + rowbase + r0 + r) * KNN + lane] =
          (int)(s_list[(r0 + r) * KNN + lane] & 0xffffffffull);
  }
}

// ---------------------------------------------------------------------------
// per-point GEMM: Y[b,n,o] = sum_c A[o*C+c] * X[(b*N+n)*S+coff+c]
// 64 pts x 64 outs per block, K-chunks of 16 staged in LDS, 4x4 per thread.
// ---------------------------------------------------------------------------
__global__ __launch_bounds__(256) void k_gemm(const float* __restrict__ A,
                                              const float* __restrict__ X,
                                              float* __restrict__ Y,
                                              int S, int coff, int C, int O2) {
  __shared__ __align__(16) float sX[16 * 68];
  __shared__ __align__(16) float sA[16 * 68];
  const int b = blockIdx.z;
  const int nb = blockIdx.x * 64;
  const int ob = blockIdx.y * 64;
  const int tid = threadIdx.x, ty = tid >> 4, tx = tid & 15;
  float acc[4][4] = {};

  for (int kc = 0; kc < C; kc += 16) {
#pragma unroll
    for (int t = 0; t < 4; ++t) {
      int v = tid + t * 256;
      int p = v >> 4, k = v & 15;
      float xv = 0.f, av = 0.f;
      if (kc + k < C) {
        xv = X[(size_t)(b * NPTS + nb + p) * S + coff + kc + k];
        av = A[(size_t)(ob + p) * C + kc + k];
      }
      sX[k * 68 + p] = xv;
      sA[k * 68 + p] = av;
    }
    __syncthreads();
#pragma unroll
    for (int kk = 0; kk < 16; ++kk) {
      float4 xa = *reinterpret_cast<const float4*>(&sX[kk * 68 + ty * 4]);
      float4 wb = *reinterpret_cast<const float4*>(&sA[kk * 68 + tx * 4]);
      acc[0][0] = fmaf(xa.x, wb.x, acc[0][0]);
      acc[0][1] = fmaf(xa.x, wb.y, acc[0][1]);
      acc[0][2] = fmaf(xa.x, wb.z, acc[0][2]);
      acc[0][3] = fmaf(xa.x, wb.w, acc[0][3]);
      acc[1][0] = fmaf(xa.y, wb.x, acc[1][0]);
      acc[1][1] = fmaf(xa.y, wb.y, acc[1][1]);
      acc[1][2] = fmaf(xa.y, wb.z, acc[1][2]);
      acc[1][3] = fmaf(xa.y, wb.w, acc[1][3]);
      acc[2][0] = fmaf(xa.z, wb.x, acc[2][0]);
      acc[2][1] = fmaf(xa.z, wb.y, acc[2][1]);
      acc[2][2] = fmaf(xa.z, wb.z, acc[2][2]);
      acc[2][3] = fmaf(xa.z, wb.w, acc[2][3]);
      acc[3][0] = fmaf(xa.w, wb.x, acc[3][0]);
      acc[3][1] = fmaf(xa.w, wb.y, acc[3][1]);
      acc[3][2] = fmaf(xa.w, wb.z, acc[3][2]);
      acc[3][3] = fmaf(xa.w, wb.w, acc[3][3]);
    }
    __syncthreads();
  }
#pragma unroll
  for (int i = 0; i < 4; ++i) {
    float4 st = make_float4(acc[i][0], acc[i][1], acc[i][2], acc[i][3]);
    *reinterpret_cast<float4*>(
        &Y[(size_t)(b * NPTS + nb + ty * 4 + i) * O2 + ob + tx * 4]) = st;
  }
}

// ---------------------------------------------------------------------------
// gather + max-over-k + BN + LeakyReLU (monotone fold):
// out = leaky(a * ((a>=0 ? max_k : min_k) U[idx_k] + V[n]) + cbias)
// UV layout [B,N,2O]: U at [..,0..O), V at [..,O..2O). Writes Xcat slice.
// ---------------------------------------------------------------------------
__global__ __launch_bounds__(256) void k_gather(const float* __restrict__ UV,
                                                const int* __restrict__ idx,
                                                const float* __restrict__ bn,
                                                float* __restrict__ Xcat,
                                                int O2, int O, int coff_out) {
  const int b = blockIdx.z;
  const int og = blockIdx.y * 64;
  const int wave = threadIdx.x >> 6, lane = threadIdx.x & 63;
  const int n = blockIdx.x * 4 + wave;
  const int o = og + lane;
  const int* ip = &idx[(size_t)(b * NPTS + n) * KNN];
  float g = bn[o], be = bn[O + o], mu = bn[2 * O + o], va = bn[3 * O + o];
  float a = g / sqrtf(va + BN_EPS);
  float cb = be - mu * a;
  float vmax = -3.4e38f, vmin = 3.4e38f;
#pragma unroll
  for (int k = 0; k < KNN; ++k) {
    int jn = ip[k];
    float v = UV[(size_t)(b * NPTS + jn) * O2 + o];
    vmax = fmaxf(vmax, v);
    vmin = fminf(vmin, v);
  }
  float Vc = UV[(size_t)(b * NPTS + n) * O2 + O + o];
  float M = ((a >= 0.f) ? vmax : vmin) + Vc;
  float z = fmaf(a, M, cb);
  Xcat[(size_t)(b * NPTS + n) * 512 + coff_out + o] = fmaxf(z, 0.2f * z);
}

// ---------------------------------------------------------------------------
// final BN + leaky + transpose [B,N,512] -> [B,512,N]
// ---------------------------------------------------------------------------
__global__ __launch_bounds__(256) void k_out(const float* __restrict__ Y,
                                             const float* __restrict__ bn,
                                             float* __restrict__ out) {
  int n = blockIdx.x * 256 + threadIdx.x;
  int o = blockIdx.y;
  int b = blockIdx.z;
  float g = bn[o], be = bn[512 + o], mu = bn[1024 + o], va = bn[1536 + o];
  float a = g / sqrtf(va + BN_EPS);
  float cb = be - mu * a;
  float y = Y[(size_t)(b * NPTS + n) * 512 + o];
  float z = fmaf(a, y, cb);
  out[(size_t)(b * 512 + o) * NPTS + n] = fmaxf(z, 0.2f * z);
}

// ---------------------------------------------------------------------------
extern "C" void kernel_launch(void* const* d_in, const int* in_sizes, int n_in,
                              void* d_out, int out_size, void* d_ws,
                              size_t ws_size, hipStream_t stream) {
  const float* x  = (const float*)d_in[0];
  const float* W1 = (const float*)d_in[1];
  const float* W2 = (const float*)d_in[2];
  const float* W3 = (const float*)d_in[3];
  const float* W4 = (const float*)d_in[4];
  const float* W5 = (const float*)d_in[5];
  const float* bn1 = (const float*)d_in[6];
  const float* bn2 = (const float*)d_in[7];
  const float* bn3 = (const float*)d_in[8];
  const float* bn4 = (const float*)d_in[9];
  const float* bn5 = (const float*)d_in[10];
  float* out = (float*)d_out;

  // workspace layout (floats); total ~17.3M floats (~69 MB)
  float* f    = (float*)d_ws;
  float* xt   = f;                        // [B,N,4]        65536
  float* nrm  = f + 65536;                // [B,N]          16384
  int*   idx  = (int*)(f + 81920);        // [B,N,20] int   327680
  float* Xcat = f + 409600;               // [B,N,512]      8388608
  float* UV   = f + 8798208;              // [B,N,512] max  8388608
  float* A2   = f + 17186816;             // [512,128] max  65536

  // XT4 (channel-block-major xj operand) aliases UV: k_tr/k_knn use it
  // strictly BEFORE k_gemm overwrites UV in each stage (stream-ordered).
  float4* XT = (float4*)UV;

  k_xt<<<64, 256, 0, stream>>>(x, xt, nrm);

  // ---- EdgeConv 1: C=3(pad 4), O=64 ----  (xt IS XT4 for C=4)
  k_prep<<<1, 256, 0, stream>>>(W1, A2, 64, 3, 4);
  k_knn<4><<<1024, 256, 0, stream>>>(xt, (const float4*)xt, nrm, 4, 0, idx);
  k_gemm<<<dim3(128, 2, 2), 256, 0, stream>>>(A2, xt, UV, 4, 0, 4, 128);
  k_gather<<<dim3(2048, 1, 2), 256, 0, stream>>>(UV, idx, bn1, Xcat, 128, 64, 0);

  // ---- EdgeConv 2: C=64, O=64 ----
  k_tr<64><<<dim3(128, 2), 256, 0, stream>>>(Xcat, 512, 0, XT, nrm);
  k_prep<<<16, 256, 0, stream>>>(W2, A2, 64, 64, 64);
  k_knn<64><<<1024, 256, 0, stream>>>(Xcat, XT, nrm, 512, 0, idx);
  k_gemm<<<dim3(128, 2, 2), 256, 0, stream>>>(A2, Xcat, UV, 512, 0, 64, 128);
  k_gather<<<dim3(2048, 1, 2), 256, 0, stream>>>(UV, idx, bn2, Xcat, 128, 64, 64);

  // ---- EdgeConv 3: C=64, O=128 ----
  k_tr<64><<<dim3(128, 2), 256, 0, stream>>>(Xcat, 512, 64, XT, nrm);
  k_prep<<<32, 256, 0, stream>>>(W3, A2, 128, 64, 64);
  k_knn<64><<<1024, 256, 0, stream>>>(Xcat, XT, nrm, 512, 64, idx);
  k_gemm<<<dim3(128, 4, 2), 256, 0, stream>>>(A2, Xcat, UV, 512, 64, 64, 256);
  k_gather<<<dim3(2048, 2, 2), 256, 0, stream>>>(UV, idx, bn3, Xcat, 256, 128, 128);

  // ---- EdgeConv 4: C=128, O=256 ----
  k_tr<128><<<dim3(128, 2), 256, 0, stream>>>(Xcat, 512, 128, XT, nrm);
  k_prep<<<128, 256, 0, stream>>>(W4, A2, 256, 128, 128);
  k_knn<128><<<1024, 256, 0, stream>>>(Xcat, XT, nrm, 512, 128, idx);
  k_gemm<<<dim3(128, 8, 2), 256, 0, stream>>>(A2, Xcat, UV, 512, 128, 128, 512);
  k_gather<<<dim3(2048, 4, 2), 256, 0, stream>>>(UV, idx, bn4, Xcat, 512, 256, 256);

  // ---- conv5 + BN + leaky, output [B,512,N] ----
  k_gemm<<<dim3(128, 8, 2), 256, 0, stream>>>(W5, Xcat, UV, 512, 0, 512, 512);
  k_out<<<dim3(32, 512, 2), 256, 0, stream>>>(UV, bn5, out);
}